// Round 1
// baseline (61.694 us; speedup 1.0000x reference)
//
#include <hip/hip_runtime.h>

#define BATCH 32
#define SGRID 32
#define SS 1024
#define NSTEPS 972

__global__ __launch_bounds__(64)
void astar_kernel(const float* __restrict__ start_maps,
                  const float* __restrict__ goal_maps,
                  const float* __restrict__ obst_maps,
                  float* __restrict__ out)
{
    const int b = blockIdx.x;
    const int lane = threadIdx.x;

    __shared__ __align__(16) float fopen_s[SS];   // f if open else +INF (key source)
    __shared__ __align__(16) float g_s[SS];
    __shared__ __align__(16) float fh_s[SS];      // 0.501f * h  (precomputed)
    __shared__ unsigned short par_s[SS];
    __shared__ unsigned char open_s[SS];
    __shared__ unsigned char hist_s[SS];
    __shared__ unsigned char obst_s[SS];
    __shared__ int sh_start, sh_goal;

    const float* st = start_maps + b * SS;
    const float* gl = goal_maps + b * SS;
    const float* ob = obst_maps + b * SS;

    // locate start & goal (one-hot inputs)
    for (int i = 0; i < 16; ++i) {
        int c = i * 64 + lane;
        if (st[c] > 0.5f) sh_start = c;
        if (gl[c] > 0.5f) sh_goal = c;
    }
    __syncthreads();
    const int start_idx = sh_start;
    const int goal_idx = sh_goal;
    const float gi = (float)(goal_idx >> 5);
    const float gj = (float)(goal_idx & 31);

    const float SQRT2F = 1.41421356237309515f;  // fl32(sqrt(2)) = 0x3FB504F3
    const float WH = 0.501f;                    // fl32(1 - 0.5 + 0.001)
    const float INFF = __int_as_float(0x7f800000);

    // init per-cell state; h = min(dx,dy)*sqrt2 + |dx-dy| (exact small-int floats)
    for (int i = 0; i < 16; ++i) {
        int c = i * 64 + lane;
        float dx = fabsf((float)(c >> 5) - gi);
        float dy = fabsf((float)(c & 31) - gj);
        float h = fminf(dx, dy) * SQRT2F + fabsf(dx - dy);
        fh_s[c] = WH * h;
        g_s[c] = 0.0f;
        par_s[c] = (unsigned short)goal_idx;
        open_s[c] = 0;
        hist_s[c] = 0;
        obst_s[c] = (ob[c] > 0.5f) ? (unsigned char)1 : (unsigned char)0;
        fopen_s[c] = INFF;
    }
    __syncthreads();
    if (lane == 0) {
        open_s[start_idx] = 1;
        fopen_s[start_idx] = fh_s[start_idx];   // f = 0.5*0 + fh
    }
    __syncthreads();

    const int base = lane * 16;

    for (int step = 0; step < NSTEPS; ++step) {
        // ---- selection: argmin over open cells, tie -> lowest flat index ----
        unsigned long long best = ~0ull;
        #pragma unroll
        for (int i = 0; i < 16; i += 4) {
            float4 f4 = *reinterpret_cast<const float4*>(&fopen_s[base + i]);
            unsigned long long k0 = ((unsigned long long)__float_as_uint(f4.x) << 10) | (unsigned)(base + i + 0);
            unsigned long long k1 = ((unsigned long long)__float_as_uint(f4.y) << 10) | (unsigned)(base + i + 1);
            unsigned long long k2 = ((unsigned long long)__float_as_uint(f4.z) << 10) | (unsigned)(base + i + 2);
            unsigned long long k3 = ((unsigned long long)__float_as_uint(f4.w) << 10) | (unsigned)(base + i + 3);
            unsigned long long a = k0 < k1 ? k0 : k1;
            unsigned long long c2 = k2 < k3 ? k2 : k3;
            unsigned long long d = a < c2 ? a : c2;
            best = d < best ? d : best;
        }
        #pragma unroll
        for (int m = 32; m >= 1; m >>= 1) {
            unsigned long long o = __shfl_xor(best, m, 64);
            best = o < best ? o : best;
        }
        const int sel = (int)(best & 1023ull);
        const bool solved = (sel == goal_idx);
        const float gsel = g_s[sel];            // LDS broadcast read
        const int si = sel >> 5, sj = sel & 31;

        if (lane == 0) {
            hist_s[sel] = 1;
            if (!solved) { open_s[sel] = 0; fopen_s[sel] = INFF; }
        }
        // 8 neighbor relaxations (sel is never its own neighbor -> no races)
        if (lane < 8) {
            int k = lane < 4 ? lane : lane + 1;       // skip center (k=4)
            int di = k / 3 - 1;
            int dj = k - (k / 3) * 3 - 1;
            int ni = si + di, nj = sj + dj;
            if ((unsigned)ni < 32u && (unsigned)nj < 32u) {
                int nb = ni * 32 + nj;
                if (obst_s[nb]) {
                    float w = (di != 0 && dj != 0) ? SQRT2F : 1.0f;
                    float g2 = gsel + w;              // exact: fl(g_sel + w)
                    bool op = open_s[nb] != 0;
                    bool hi = hist_s[nb] != 0;
                    bool relax = (!op && !hi) || (op && (g_s[nb] > g2));
                    if (relax) {
                        g_s[nb] = g2;
                        open_s[nb] = 1;
                        par_s[nb] = (unsigned short)sel;
                        fopen_s[nb] = 0.5f * g2 + fh_s[nb];   // f = fl(0.5*g + fh)
                    }
                }
            }
        }
        __syncthreads();
        if (solved) break;   // exact: state provably constant after goal selection
    }

    float* out_hist = out + b * SS;
    float* out_path = out + BATCH * SS + b * SS;
    float* out_g    = out + 2 * BATCH * SS + b * SS;
    for (int i = 0; i < 16; ++i) {
        int c = i * 64 + lane;
        out_hist[c] = hist_s[c] ? 1.0f : 0.0f;
        out_g[c]    = g_s[c];
        out_path[c] = (c == goal_idx) ? 1.0f : 0.0f;
    }
    __syncthreads();   // order init stores before backtrack marks
    if (lane == 0) {
        int loc = par_s[goal_idx];
        for (int it = 0; it < NSTEPS; ++it) {
            out_path[loc] = 1.0f;
            if (loc == goal_idx) break;   // parent chain strictly decreasing in time
            loc = par_s[loc];
        }
    }
}

extern "C" void kernel_launch(void* const* d_in, const int* in_sizes, int n_in,
                              void* d_out, int out_size, void* d_ws, size_t ws_size,
                              hipStream_t stream)
{
    // d_in: [0]=cost_maps (unused in 'default' mode), [1]=start, [2]=goal, [3]=obstacles
    const float* start_maps = (const float*)d_in[1];
    const float* goal_maps  = (const float*)d_in[2];
    const float* obst_maps  = (const float*)d_in[3];
    float* out = (float*)d_out;
    hipLaunchKernelGGL(astar_kernel, dim3(BATCH), dim3(64), 0, stream,
                       start_maps, goal_maps, obst_maps, out);
}

// Round 2
// 51.680 us; speedup vs baseline: 1.1938x; 1.1938x over previous
//
#include <hip/hip_runtime.h>

#define BATCH 32
#define SGRID 32
#define SS 1024
#define NSTEPS 972

__device__ __forceinline__ unsigned umin2(unsigned a, unsigned b) { return a < b ? a : b; }

// Full 64-lane unsigned-min, result broadcast via readlane(lane 63) -> SGPR.
// DPP chain: xor1 (quad_perm 1,0,3,2), xor2 (quad_perm 2,3,0,1),
// row_half_mirror (merge 4->8), row_mirror (merge 8->16),
// row_bcast15 (row0->row1, row2->row3), row_bcast31 (rows01 -> rows23).
__device__ __forceinline__ unsigned wave_min_bcast_u32(unsigned v) {
    unsigned t;
    t = (unsigned)__builtin_amdgcn_update_dpp((int)v, (int)v, 0xB1,  0xF, 0xF, false); v = umin2(v, t);
    t = (unsigned)__builtin_amdgcn_update_dpp((int)v, (int)v, 0x4E,  0xF, 0xF, false); v = umin2(v, t);
    t = (unsigned)__builtin_amdgcn_update_dpp((int)v, (int)v, 0x141, 0xF, 0xF, false); v = umin2(v, t);
    t = (unsigned)__builtin_amdgcn_update_dpp((int)v, (int)v, 0x140, 0xF, 0xF, false); v = umin2(v, t);
    t = (unsigned)__builtin_amdgcn_update_dpp((int)v, (int)v, 0x142, 0xF, 0xF, false); v = umin2(v, t);
    t = (unsigned)__builtin_amdgcn_update_dpp((int)v, (int)v, 0x143, 0xF, 0xF, false); v = umin2(v, t);
    return (unsigned)__builtin_amdgcn_readlane((int)v, 63);   // lane 63 holds full min
}

__global__ __launch_bounds__(64)
void astar_kernel(const float* __restrict__ start_maps,
                  const float* __restrict__ goal_maps,
                  const float* __restrict__ obst_maps,
                  float* __restrict__ out)
{
    const int b = blockIdx.x;
    const int lane = threadIdx.x;

    __shared__ __align__(16) float fopen_s[SS];   // f if open else +INF (argmin source)
    __shared__ __align__(16) float g_s[SS];
    __shared__ __align__(16) float fh_s[SS];      // 0.501f * h  (precomputed)
    __shared__ unsigned short par_s[SS];
    __shared__ unsigned char open_s[SS];
    __shared__ unsigned char hist_s[SS];
    __shared__ unsigned char obst_s[SS];
    __shared__ int sh_start, sh_goal;

    const float* st = start_maps + b * SS;
    const float* gl = goal_maps + b * SS;
    const float* ob = obst_maps + b * SS;

    // locate start & goal (one-hot inputs)
    for (int i = 0; i < 16; ++i) {
        int c = i * 64 + lane;
        if (st[c] > 0.5f) sh_start = c;
        if (gl[c] > 0.5f) sh_goal = c;
    }
    __syncthreads();
    const int start_idx = sh_start;
    const int goal_idx = sh_goal;
    const float gi = (float)(goal_idx >> 5);
    const float gj = (float)(goal_idx & 31);

    const float SQRT2F = 1.41421356237309515f;  // fl32(sqrt(2)) = 0x3FB504F3
    const float WH = 0.501f;                    // fl32(1 - 0.5 + 0.001)
    const float INFF = __int_as_float(0x7f800000);

    for (int i = 0; i < 16; ++i) {
        int c = i * 64 + lane;
        float dx = fabsf((float)(c >> 5) - gi);
        float dy = fabsf((float)(c & 31) - gj);
        float h = fminf(dx, dy) * SQRT2F + fabsf(dx - dy);
        fh_s[c] = WH * h;
        g_s[c] = 0.0f;
        par_s[c] = (unsigned short)goal_idx;
        open_s[c] = 0;
        hist_s[c] = 0;
        obst_s[c] = (ob[c] > 0.5f) ? (unsigned char)1 : (unsigned char)0;
        fopen_s[c] = INFF;
    }
    __syncthreads();
    if (lane == 0) {
        open_s[start_idx] = 1;
        fopen_s[start_idx] = fh_s[start_idx];   // f = 0.5*0 + fh
    }
    __syncthreads();

    const int base = lane * 16;

    for (int step = 0; step < NSTEPS; ++step) {
        // ---- local argmin over this lane's 16 open-f values (tie -> lowest idx) ----
        unsigned long long best = ~0ull;
        #pragma unroll
        for (int i = 0; i < 16; i += 4) {
            float4 f4 = *reinterpret_cast<const float4*>(&fopen_s[base + i]);
            unsigned long long k0 = ((unsigned long long)__float_as_uint(f4.x) << 10) | (unsigned)(base + i + 0);
            unsigned long long k1 = ((unsigned long long)__float_as_uint(f4.y) << 10) | (unsigned)(base + i + 1);
            unsigned long long k2 = ((unsigned long long)__float_as_uint(f4.z) << 10) | (unsigned)(base + i + 2);
            unsigned long long k3 = ((unsigned long long)__float_as_uint(f4.w) << 10) | (unsigned)(base + i + 3);
            unsigned long long a = k0 < k1 ? k0 : k1;
            unsigned long long c2 = k2 < k3 ? k2 : k3;
            unsigned long long d = a < c2 ? a : c2;
            best = d < best ? d : best;
        }
        const int bidx = (int)(best & 1023ull);
        const unsigned bf = (unsigned)(best >> 10);      // f_bits of local best (f>=0 -> uint order == float order)

        // prefetch local best's g: winner's value picked up by readlane; load latency
        // hides under the DPP reduction below
        const float bg = g_s[bidx];

        // ---- global min via DPP butterfly (VALU pipe, no LDS round-trips) ----
        const unsigned gmin = wave_min_bcast_u32(bf);
        const unsigned long long m = __ballot(bf == gmin);
        const int wl = (int)__builtin_ctzll(m);          // lowest lane == lowest cell idx among ties
        const int sel = __builtin_amdgcn_readlane(bidx, wl);
        const float gsel = __uint_as_float((unsigned)__builtin_amdgcn_readlane((int)__float_as_uint(bg), wl));

        const bool solved = (sel == goal_idx);
        const int si = sel >> 5, sj = sel & 31;

        if (lane == 0) {
            hist_s[sel] = 1;
            if (!solved) { open_s[sel] = 0; fopen_s[sel] = INFF; }
        }
        // 8 neighbor relaxations (sel is never its own neighbor -> no races)
        if (lane < 8) {
            int k = lane < 4 ? lane : lane + 1;       // skip center (k=4)
            int di = k / 3 - 1;
            int dj = k - (k / 3) * 3 - 1;
            int ni = si + di, nj = sj + dj;
            if ((unsigned)ni < 32u && (unsigned)nj < 32u) {
                int nb = ni * 32 + nj;
                if (obst_s[nb]) {
                    float w = (di != 0 && dj != 0) ? SQRT2F : 1.0f;
                    float g2 = gsel + w;              // exact: fl(g_sel + w)
                    bool op = open_s[nb] != 0;
                    bool hi = hist_s[nb] != 0;
                    bool relax = (!op && !hi) || (op && (g_s[nb] > g2));
                    if (relax) {
                        g_s[nb] = g2;
                        open_s[nb] = 1;
                        par_s[nb] = (unsigned short)sel;
                        fopen_s[nb] = 0.5f * g2 + fh_s[nb];   // f = fl(0.5*g + fh)
                    }
                }
            }
        }
        // single wave per block: DS ops are in-order per wave; this fence both
        // drains lgkm and stops the compiler reordering LDS ops across it
        asm volatile("s_waitcnt lgkmcnt(0)" ::: "memory");
        if (solved) break;   // exact: state provably constant after goal selection
    }

    float* out_hist = out + b * SS;
    float* out_path = out + BATCH * SS + b * SS;
    float* out_g    = out + 2 * BATCH * SS + b * SS;
    for (int i = 0; i < 16; ++i) {
        int c = i * 64 + lane;
        out_hist[c] = hist_s[c] ? 1.0f : 0.0f;
        out_g[c]    = g_s[c];
        out_path[c] = (c == goal_idx) ? 1.0f : 0.0f;
    }
    __syncthreads();   // drain vmcnt: init stores ordered before backtrack marks
    if (lane == 0) {
        int loc = par_s[goal_idx];
        for (int it = 0; it < NSTEPS; ++it) {
            out_path[loc] = 1.0f;
            if (loc == goal_idx) break;   // parent chain strictly decreasing in time
            loc = par_s[loc];
        }
    }
}

extern "C" void kernel_launch(void* const* d_in, const int* in_sizes, int n_in,
                              void* d_out, int out_size, void* d_ws, size_t ws_size,
                              hipStream_t stream)
{
    // d_in: [0]=cost_maps (unused in 'default' mode), [1]=start, [2]=goal, [3]=obstacles
    const float* start_maps = (const float*)d_in[1];
    const float* goal_maps  = (const float*)d_in[2];
    const float* obst_maps  = (const float*)d_in[3];
    float* out = (float*)d_out;
    hipLaunchKernelGGL(astar_kernel, dim3(BATCH), dim3(64), 0, stream,
                       start_maps, goal_maps, obst_maps, out);
}